// Round 10
// baseline (255.807 us; speedup 1.0000x reference)
//
#include <hip/hip_runtime.h>
#include <hip/hip_bf16.h>
#include <math.h>

// Tucker MoE: T=1024, D=1024, DFF=1024, R=64, G=8, E=32, NEXP=256, K=8, F=8192
// Round 10: fused router done right (vs R4's 95us failure): 256 blocks x 1024
// threads = 16 waves/CU. Thread (e, kc) computes a K=256 slice of 4 tokens'
// logits; LDS fold is left-chained over 8x128 partials = BIT-IDENTICAL to the
// R6/R9 split-K router (no selection-flip risk). lp (16 MB traffic) deleted;
// scan merged into L2. 6 dispatches + 1 KB memset:
//  L1 k_prep_router : casts/transposes || logits+topk+rank (in-register)
//  L2 k_pre_scan    : pre MFMA (split-K 2) || 256-entry scan -> off
//  L3 k_core_gu     : f-indexed fold pre + gate/up core (fp32) -> xgb/xub[p]
//  L4 k_fused_ad    : act(gate/up MFMA + silu*mul in LDS) fused w/ down MFMA
//  L5 k_down_accY   : fold xdp + down core + weighted token fold -> Y bf16
//  L6 k_fin         : dense out = Y[1024,512] @ Uod2[512,1024] (bf16 MFMA)

#define T_ 1024
#define D_ 1024
#define DFF_ 1024
#define R_ 64
#define G_ 8
#define E_ 32
#define NEXP_ 256
#define K_ 8
#define F_ 8192
#define PKZ_ 2   // k_pre split-K
#define DKZ_ 4   // down split-K (chunks of 256 over DFF)
#define LP_ 72   // LDS tile pitch in bf16 elems (16B rows, 2-way bank alias = free)

typedef short bf16x8 __attribute__((ext_vector_type(8)));
typedef float f32x4 __attribute__((ext_vector_type(4)));

__device__ __forceinline__ unsigned short f2bf(float f) {
  unsigned int u = __float_as_uint(f);
  u += 0x7fffu + ((u >> 16) & 1u);  // RNE (finite inputs)
  return (unsigned short)(u >> 16);
}

__device__ __forceinline__ void stage_tile(short* dst, const unsigned short* src,
                                           int gp, int tid) {
  for (int idx = tid; idx < 512; idx += 256) {
    int r = idx >> 3, c8 = (idx & 7) << 3;
    *(uint4*)&dst[r * LP_ + c8] = *(const uint4*)&src[(size_t)r * gp + c8];
  }
}

__device__ __forceinline__ void stage_tile_guard(short* dst, const unsigned short* src,
                                                 int gp, int rows_valid, int tid) {
  for (int idx = tid; idx < 512; idx += 256) {
    int r = idx >> 3, c8 = (idx & 7) << 3;
    uint4 v = make_uint4(0u, 0u, 0u, 0u);
    if (r < rows_valid) v = *(const uint4*)&src[(size_t)r * gp + c8];
    *(uint4*)&dst[r * LP_ + c8] = v;
  }
}

// Wave computes a 16x64 strip (rows [ms,ms+16)) over K=64 from LDS tiles
// As (rows=m, k-contig) and Bs (rows=n, k-contig; i.e. B^T).
__device__ __forceinline__ void mma_strip(const short* As, const short* Bs,
                                          int ms, int lane, f32x4* acc) {
  int lm = lane & 15;
  int lk = (lane >> 4) << 3;
#pragma unroll
  for (int kc = 0; kc < 64; kc += 32) {
    bf16x8 a = *(const bf16x8*)&As[(ms + lm) * LP_ + kc + lk];
#pragma unroll
    for (int nt = 0; nt < 4; ++nt) {
      bf16x8 b = *(const bf16x8*)&Bs[(nt * 16 + lm) * LP_ + kc + lk];
      acc[nt] = __builtin_amdgcn_mfma_f32_16x16x32_bf16(a, b, acc[nt], 0, 0, 0);
    }
  }
}

// ---------------------------------------------------------------- L1: prep || router
// 1152 blocks x 1024 thr. b<896 = prep roles (id=b>>7: 0..4 cast+T,
// 5 = uout_down -> Uod2T[d][g*64+r], 6 = x cast); b>=896 = fused router:
// 4 tokens/block, logits in registers, LDS fold (bit-identical to split-K
// order), per-wave top-k + softmax + rank.
__global__ __launch_bounds__(1024) void k_prep_router(
    const float* __restrict__ x, const float* __restrict__ Wg,
    const float* __restrict__ s0, const float* __restrict__ s1,
    const float* __restrict__ s2, const float* __restrict__ s3,
    const float* __restrict__ s4, const float* __restrict__ s5,
    unsigned short* __restrict__ xb,
    unsigned short* __restrict__ d0, unsigned short* __restrict__ d1,
    unsigned short* __restrict__ d2, unsigned short* __restrict__ d3,
    unsigned short* __restrict__ d4, unsigned short* __restrict__ d5,
    int* __restrict__ cnt, int* __restrict__ sel,
    float* __restrict__ wsm, int* __restrict__ rank) {
  __shared__ float shbuf[12288];  // router: xs[4][1024] + part[8][256][4]; prep: ts[64][65]
  int b = blockIdx.x;
  int tid = threadIdx.x;
  if (b < 896) {
    int id = b >> 7, rem = b & 127, g = rem >> 4, tile = rem & 15;
    if (id == 6) {
      size_t base = ((size_t)g * 16 + tile) * 8192;
      for (int i = tid; i < 2048; i += 1024) {
        size_t idx = base + (size_t)i * 4;
        float4 v = *(const float4*)&x[idx];
        xb[idx + 0] = f2bf(v.x);
        xb[idx + 1] = f2bf(v.y);
        xb[idx + 2] = f2bf(v.z);
        xb[idx + 3] = f2bf(v.w);
      }
      return;
    }
    const float* src = id == 0 ? s0 : id == 1 ? s1 : id == 2 ? s2 : id == 3 ? s3 : id == 4 ? s4 : s5;
    unsigned short* dst = id == 0 ? d0 : id == 1 ? d1 : id == 2 ? d2 : id == 3 ? d3 : id == 4 ? d4 : d5;
    if (id < 3) {
      // uin*: src [g][1024][64] -> dst [g][64][1024]
      int r0 = tile * 64;
      for (int idx = tid; idx < 4096; idx += 1024) {
        int r = idx >> 6, c = idx & 63;
        shbuf[r * 65 + c] = src[((size_t)g * 1024 + r0 + r) * 64 + c];
      }
      __syncthreads();
      for (int idx = tid; idx < 4096; idx += 1024) {
        int c = idx >> 6, r = idx & 63;
        dst[((size_t)g * 64 + c) * 1024 + r0 + r] = f2bf(shbuf[r * 65 + c]);
      }
    } else {
      // uout*: src [g][64][1024]; id 3/4 -> [g][1024][64]; id 5 -> [d][g*64+r]
      int c0 = tile * 64;
      for (int idx = tid; idx < 4096; idx += 1024) {
        int r = idx >> 6, c = idx & 63;
        shbuf[r * 65 + c] = src[((size_t)g * 64 + r) * 1024 + c0 + c];
      }
      __syncthreads();
      if (id == 5) {
        for (int idx = tid; idx < 4096; idx += 1024) {
          int c = idx >> 6, r = idx & 63;
          dst[(size_t)(c0 + c) * 512 + g * 64 + r] = f2bf(shbuf[r * 65 + c]);
        }
      } else {
        for (int idx = tid; idx < 4096; idx += 1024) {
          int c = idx >> 6, r = idx & 63;
          dst[((size_t)g * 1024 + c0 + c) * 64 + r] = f2bf(shbuf[r * 65 + c]);
        }
      }
    }
    return;
  }
  // ---- fused router: 4 tokens/block
  int rb = b - 896;           // 0..255
  int t0 = rb * 4;
  int e = tid & 255;
  int kc = tid >> 8;          // 0..3 (K-chunk of 256)
  float* xs = shbuf;          // [4][1024]
  {
    int tl = tid >> 8, d = (tid & 255) * 4;
    *(float4*)&xs[tl * 1024 + d] = *(const float4*)&x[(size_t)(t0 + tl) * D_ + d];
  }
  __syncthreads();
  // two 128-length accumulators per chunk -> 8 partials total, matching the
  // R9 split-K (chunks of 128, ascending d) summation bit-exactly.
  float alo[4] = {}, ahi[4] = {};
  int dbase = kc * 256;
#pragma unroll 8
  for (int d2 = 0; d2 < 128; ++d2) {
    float wv = Wg[(size_t)(dbase + d2) * NEXP_ + e];
#pragma unroll
    for (int j = 0; j < 4; ++j) alo[j] = fmaf(xs[j * 1024 + dbase + d2], wv, alo[j]);
  }
#pragma unroll 8
  for (int d2 = 128; d2 < 256; ++d2) {
    float wv = Wg[(size_t)(dbase + d2) * NEXP_ + e];
#pragma unroll
    for (int j = 0; j < 4; ++j) ahi[j] = fmaf(xs[j * 1024 + dbase + d2], wv, ahi[j]);
  }
  float* part = shbuf + 4096;  // [8][256][4]
#pragma unroll
  for (int j = 0; j < 4; ++j) {
    part[(2 * kc) * 1024 + e * 4 + j] = alo[j];
    part[(2 * kc + 1) * 1024 + e * 4 + j] = ahi[j];
  }
  __syncthreads();
  // left-chain fold z=0..7 (same order as R9's topk partial fold)
  {
    int j = tid >> 8;
    float s = 0.f;
#pragma unroll
    for (int z = 0; z < 8; ++z) s += part[z * 1024 + e * 4 + j];
    shbuf[j * 256 + e] = s;  // lg[j][e]; xs region is dead
  }
  __syncthreads();
  int w = tid >> 6;
  if (w < 4) {
    int lane = tid & 63;
    int t = t0 + w;
    const float* lg = shbuf + w * 256;
    float v[4];
    int idx[4];
#pragma unroll
    for (int j = 0; j < 4; ++j) { idx[j] = lane + 64 * j; v[j] = lg[idx[j]]; }
    float topv[K_];
    int topi[K_];
#pragma unroll
    for (int k = 0; k < K_; ++k) {
      float bv = v[0];
      int bi = idx[0];
#pragma unroll
      for (int j = 1; j < 4; ++j)
        if (v[j] > bv || (v[j] == bv && idx[j] < bi)) { bv = v[j]; bi = idx[j]; }
#pragma unroll
      for (int off = 32; off > 0; off >>= 1) {
        float ov = __shfl_xor(bv, off);
        int oi = __shfl_xor(bi, off);
        if (ov > bv || (ov == bv && oi < bi)) { bv = ov; bi = oi; }
      }
      topv[k] = bv;
      topi[k] = bi;
#pragma unroll
      for (int j = 0; j < 4; ++j)
        if (idx[j] == bi) v[j] = -INFINITY;
    }
    float m = topv[0];
    float ev[K_];
    float s = 0.f;
#pragma unroll
    for (int k = 0; k < K_; ++k) { ev[k] = expf(topv[k] - m); s += ev[k]; }
    float inv = 1.f / s;
    if (lane < K_) {
      sel[t * K_ + lane] = topi[lane];
      wsm[t * K_ + lane] = ev[lane] * inv;
      rank[t * K_ + lane] = atomicAdd(&cnt[topi[lane]], 1);
    }
  }
}

// ---------------------------------------------------------------- L2: pre MFMA || scan
// 513 blocks x 256 thr: b<512 = pre (split-K 2); b==512 = 256-entry scan.
__global__ __launch_bounds__(256) void k_pre_scan(
    const unsigned short* __restrict__ xb,
    const unsigned short* __restrict__ uinT_g, const unsigned short* __restrict__ uinT_u,
    float* __restrict__ Pgp, float* __restrict__ Pup,
    const int* __restrict__ cnt, int* __restrict__ off) {
  __shared__ short sh2[2 * 64 * LP_];
  __shared__ int ssc[NEXP_];
  int b = blockIdx.x;
  if (b < 512) {
    int tile = b & 15, g = (b >> 4) & 7, zz = b >> 7;
    int gu = zz >> 1, kz = zz & 1;
    const unsigned short* U = gu ? uinT_u : uinT_g;  // [G][64(r)][1024(d)]
    float* P = gu ? Pup : Pgp;
    int t0 = tile * 64;
    short* As = sh2;
    short* Bs = sh2 + 64 * LP_;
    int tid = threadIdx.x, lane = tid & 63, ms = (tid >> 6) * 16;
    f32x4 acc[4] = {};
    int dlo = kz * (D_ / PKZ_);
    for (int dc = dlo; dc < dlo + D_ / PKZ_; dc += 64) {
      stage_tile(As, xb + (size_t)t0 * D_ + dc, D_, tid);
      stage_tile(Bs, U + (size_t)g * 64 * 1024 + dc, 1024, tid);
      __syncthreads();
      mma_strip(As, Bs, ms, lane, acc);
      __syncthreads();
    }
    int lm = lane & 15, lq = (lane >> 4) * 4;
#pragma unroll
    for (int nt = 0; nt < 4; ++nt)
#pragma unroll
      for (int r = 0; r < 4; ++r)
        P[((size_t)(kz * G_ + g) * T_ + t0 + ms + lq + r) * R_ + nt * 16 + lm] = acc[nt][r];
    return;
  }
  // ---- scan block
  int i = threadIdx.x;
  ssc[i] = cnt[i];
  __syncthreads();
  for (int d = 1; d < NEXP_; d <<= 1) {
    int v = (i >= d) ? ssc[i - d] : 0;
    __syncthreads();
    ssc[i] += v;
    __syncthreads();
  }
  off[i + 1] = ssc[i];
  if (i == 0) off[0] = 0;
}

// ---------------------------------------------------------------- L3: f-indexed fold pre + gate/up core -> xgb/xub[p]
__global__ __launch_bounds__(256) void k_core_gu(const float* __restrict__ Pgp,
                                                 const float* __restrict__ Pup,
                                                 const float* __restrict__ core_g,
                                                 const float* __restrict__ core_u,
                                                 const int* __restrict__ sel,
                                                 const int* __restrict__ rank,
                                                 const int* __restrict__ off,
                                                 unsigned short* __restrict__ xgb,
                                                 unsigned short* __restrict__ xub) {
  int pl = threadIdx.x >> 6;
  int o = threadIdx.x & 63;
  int f = blockIdx.x * 4 + pl;
  int t = f >> 3;
  int e = sel[f];
  int g = e >> 5;
  int p = off[e] + rank[f];
  __shared__ float rg[4][64], ru[4][64];
  float sg = 0.f, su = 0.f;
#pragma unroll
  for (int kz = 0; kz < PKZ_; ++kz) {
    sg += Pgp[((size_t)(kz * G_ + g) * T_ + t) * R_ + o];
    su += Pup[((size_t)(kz * G_ + g) * T_ + t) * R_ + o];
  }
  rg[pl][o] = sg;
  ru[pl][o] = su;
  __syncthreads();
  const float* cg = core_g + (size_t)e * R_ * R_;
  const float* cu = core_u + (size_t)e * R_ * R_;
  float ag = 0.f, au = 0.f;
#pragma unroll 8
  for (int r = 0; r < R_; ++r) {
    ag = fmaf(rg[pl][r], cg[r * R_ + o], ag);
    au = fmaf(ru[pl][r], cu[r * R_ + o], au);
  }
  xgb[(size_t)p * R_ + o] = f2bf(ag);
  xub[(size_t)p * R_ + o] = f2bf(au);
}

// ---------------------------------------------------------------- L4: fused act+down (MFMA)
__global__ __launch_bounds__(256) void k_fused_ad(const unsigned short* __restrict__ xgb,
                                                  const unsigned short* __restrict__ xub,
                                                  const unsigned short* __restrict__ uoutT_g,
                                                  const unsigned short* __restrict__ uoutT_u,
                                                  const unsigned short* __restrict__ uinT_d,
                                                  const int* __restrict__ off,
                                                  float* __restrict__ xdp) {
  int g = blockIdx.y;
  int kz = blockIdx.z;
  int p0 = off[g * E_];
  int pend = off[g * E_ + E_];
  int ntiles = (pend - p0 + 63) >> 6;
  __shared__ short Ag[64 * LP_], Au[64 * LP_];
  __shared__ short Bg[64 * LP_], Bu[64 * LP_], Bd[64 * LP_];
  __shared__ short Pt[64 * LP_];
  int tid = threadIdx.x, lane = tid & 63, ms = (tid >> 6) * 16;
  int lm = lane & 15, lq = (lane >> 4) * 4;
  for (int tile = blockIdx.x; tile < ntiles; tile += gridDim.x) {
    int pbase = p0 + tile * 64;
    int rv = pend - pbase; if (rv > 64) rv = 64;
    stage_tile_guard(Ag, xgb + (size_t)pbase * R_, R_, rv, tid);
    stage_tile_guard(Au, xub + (size_t)pbase * R_, R_, rv, tid);
    f32x4 accd[4] = {};
#pragma unroll
    for (int c4 = 0; c4 < 4; ++c4) {
      int cc = kz * (DFF_ / DKZ_) + c4 * 64;
      stage_tile(Bg, uoutT_g + ((size_t)g * DFF_ + cc) * R_, R_, tid);
      stage_tile(Bu, uoutT_u + ((size_t)g * DFF_ + cc) * R_, R_, tid);
      stage_tile(Bd, uinT_d + (size_t)g * 64 * 1024 + cc, 1024, tid);
      __syncthreads();
      f32x4 accg[4] = {}, accu[4] = {};
      mma_strip(Ag, Bg, ms, lane, accg);
      mma_strip(Au, Bu, ms, lane, accu);
#pragma unroll
      for (int nt = 0; nt < 4; ++nt)
#pragma unroll
        for (int r = 0; r < 4; ++r) {
          float gv = accg[nt][r];
          float av = gv / (1.f + expf(-gv)) * accu[nt][r];
          Pt[(ms + lq + r) * LP_ + nt * 16 + lm] = (short)f2bf(av);
        }
      mma_strip(Pt, Bd, ms, lane, accd);  // reads only own-wave rows of Pt
      __syncthreads();
    }
#pragma unroll
    for (int nt = 0; nt < 4; ++nt)
#pragma unroll
      for (int r = 0; r < 4; ++r) {
        int p = pbase + ms + lq + r;
        if (p < pend) xdp[((size_t)kz * F_ + p) * R_ + nt * 16 + lm] = accd[nt][r];
      }
    __syncthreads();
  }
}

// ---------------------------------------------------------------- L5: fold xdp + down core + token fold -> Y bf16
// 1024 blocks = 1 token each. Wave w handles k = 2w, 2w+1 (lane = r/output o).
__global__ __launch_bounds__(256) void k_down_accY(const float* __restrict__ xdp,
                                                   const float* __restrict__ core_d,
                                                   const int* __restrict__ sel,
                                                   const int* __restrict__ rank,
                                                   const float* __restrict__ wsm,
                                                   const int* __restrict__ off,
                                                   unsigned short* __restrict__ Ybf) {
  int t = blockIdx.x;
  int w = threadIdx.x >> 6, o = threadIdx.x & 63;
  __shared__ float xs[4][64];
  __shared__ float yl[4][G_][64];
  float y[G_] = {};
#pragma unroll
  for (int kk = 0; kk < 2; ++kk) {
    int f = t * K_ + w * 2 + kk;
    int e = sel[f];
    int g = e >> 5;
    int p = off[e] + rank[f];
    float s = 0.f;
#pragma unroll
    for (int kz = 0; kz < DKZ_; ++kz) s += xdp[((size_t)kz * F_ + p) * R_ + o];
    __syncthreads();
    xs[w][o] = s;
    __syncthreads();
    const float* cd = core_d + (size_t)e * R_ * R_;
    float a = 0.f;
#pragma unroll 8
    for (int r = 0; r < R_; ++r) a = fmaf(xs[w][r], cd[r * R_ + o], a);
    y[g] += wsm[f] * a;
  }
#pragma unroll
  for (int g = 0; g < G_; ++g) yl[w][g][o] = y[g];
  __syncthreads();
  for (int idx = threadIdx.x; idx < 512; idx += 256) {
    int g = idx >> 6, oo = idx & 63;
    float v = yl[0][g][oo] + yl[1][g][oo] + yl[2][g][oo] + yl[3][g][oo];
    Ybf[(size_t)t * 512 + g * 64 + oo] = f2bf(v);
  }
}

// ---------------------------------------------------------------- L6: out = Y[1024,512] @ Uod2[512,1024], dense MFMA
__global__ __launch_bounds__(256) void k_fin(const unsigned short* __restrict__ Ybf,
                                             const unsigned short* __restrict__ Uod2T,
                                             float* __restrict__ out) {
  int t0 = blockIdx.x * 64;
  int d0 = blockIdx.y * 64;
  __shared__ short As[64 * LP_], Bs[64 * LP_];
  __shared__ float Os[64 * 68];
  int tid = threadIdx.x, lane = tid & 63, ms = (tid >> 6) * 16;
  int lm = lane & 15, lq = (lane >> 4) * 4;
  f32x4 acc[4] = {};
  for (int kc = 0; kc < 512; kc += 64) {
    stage_tile(As, Ybf + (size_t)t0 * 512 + kc, 512, tid);
    stage_tile(Bs, Uod2T + (size_t)d0 * 512 + kc, 512, tid);
    __syncthreads();
    mma_strip(As, Bs, ms, lane, acc);
    __syncthreads();
  }
#pragma unroll
  for (int nt = 0; nt < 4; ++nt)
#pragma unroll
    for (int r = 0; r < 4; ++r)
      Os[(ms + lq + r) * 68 + nt * 16 + lm] = acc[nt][r];
  __syncthreads();
  for (int idx = tid; idx < 1024; idx += 256) {
    int r = idx >> 4, c4 = (idx & 15) << 2;
    *(float4*)&out[(size_t)(t0 + r) * D_ + d0 + c4] = *(const float4*)&Os[r * 68 + c4];
  }
}

// ================================================================ launch
extern "C" void kernel_launch(void* const* d_in, const int* in_sizes, int n_in,
                              void* d_out, int out_size, void* d_ws, size_t ws_size,
                              hipStream_t stream) {
  const float* x = (const float*)d_in[0];
  const float* Wg = (const float*)d_in[1];
  const float* uin_gate = (const float*)d_in[2];
  const float* core_gate = (const float*)d_in[3];
  const float* uout_gate = (const float*)d_in[4];
  const float* uin_up = (const float*)d_in[5];
  const float* core_up = (const float*)d_in[6];
  const float* uout_up = (const float*)d_in[7];
  const float* uin_down = (const float*)d_in[8];
  const float* core_down = (const float*)d_in[9];
  const float* uout_down = (const float*)d_in[10];
  float* out = (float*)d_out;

  char* ws = (char*)d_ws;
  size_t o = 0;
  auto alloc = [&](size_t bytes) { size_t r = o; o = (o + bytes + 255) & ~(size_t)255; return r; };
  size_t o_sel = alloc(F_ * 4);
  size_t o_wsm = alloc(F_ * 4);
  size_t o_rank = alloc(F_ * 4);
  size_t o_cnt = alloc(NEXP_ * 4);
  size_t o_off = alloc((NEXP_ + 1) * 4);
  size_t o_xb = alloc((size_t)T_ * D_ * 2);                     // 2 MB
  size_t o_uinT_g = alloc((size_t)G_ * 64 * 1024 * 2);          // 1 MB each
  size_t o_uinT_u = alloc((size_t)G_ * 64 * 1024 * 2);
  size_t o_uinT_d = alloc((size_t)G_ * 64 * 1024 * 2);
  size_t o_uoutT_g = alloc((size_t)G_ * 1024 * 64 * 2);
  size_t o_uoutT_u = alloc((size_t)G_ * 1024 * 64 * 2);
  size_t o_Uod2T = alloc((size_t)D_ * 512 * 2);                 // 1 MB
  size_t o_xgb = alloc((size_t)F_ * R_ * 2);                    // 1 MB
  size_t o_xub = alloc((size_t)F_ * R_ * 2);
  size_t o_Y = alloc((size_t)T_ * 512 * 2);                     // 1 MB
  size_t o_pgp = alloc((size_t)PKZ_ * G_ * T_ * R_ * 4);        // 4 MB
  size_t o_pup = alloc((size_t)PKZ_ * G_ * T_ * R_ * 4);        // 4 MB
  size_t o_xdp = alloc((size_t)DKZ_ * F_ * R_ * 4);             // 8 MB
  (void)ws_size;

  int* sel = (int*)(ws + o_sel);
  float* wsm = (float*)(ws + o_wsm);
  int* rank = (int*)(ws + o_rank);
  int* cnt = (int*)(ws + o_cnt);
  int* off = (int*)(ws + o_off);
  unsigned short* xb = (unsigned short*)(ws + o_xb);
  unsigned short* uinT_g = (unsigned short*)(ws + o_uinT_g);
  unsigned short* uinT_u = (unsigned short*)(ws + o_uinT_u);
  unsigned short* uinT_d = (unsigned short*)(ws + o_uinT_d);
  unsigned short* uoutT_g = (unsigned short*)(ws + o_uoutT_g);
  unsigned short* uoutT_u = (unsigned short*)(ws + o_uoutT_u);
  unsigned short* Uod2T = (unsigned short*)(ws + o_Uod2T);
  unsigned short* xgb = (unsigned short*)(ws + o_xgb);
  unsigned short* xub = (unsigned short*)(ws + o_xub);
  unsigned short* Ybf = (unsigned short*)(ws + o_Y);
  float* pgp = (float*)(ws + o_pgp);
  float* pup = (float*)(ws + o_pup);
  float* xdp = (float*)(ws + o_xdp);

  hipMemsetAsync(cnt, 0, NEXP_ * 4, stream);

  k_prep_router<<<1152, 1024, 0, stream>>>(x, Wg, uin_gate, uin_up, uin_down,
                                           uout_gate, uout_up, uout_down, xb,
                                           uinT_g, uinT_u, uinT_d,
                                           uoutT_g, uoutT_u, Uod2T,
                                           cnt, sel, wsm, rank);
  k_pre_scan<<<513, 256, 0, stream>>>(xb, uinT_g, uinT_u, pgp, pup, cnt, off);
  k_core_gu<<<F_ / 4, 256, 0, stream>>>(pgp, pup, core_gate, core_up, sel, rank, off, xgb, xub);
  k_fused_ad<<<dim3(16, G_, DKZ_), 256, 0, stream>>>(xgb, xub, uoutT_g, uoutT_u, uinT_d, off, xdp);
  k_down_accY<<<T_, 256, 0, stream>>>(xdp, core_down, sel, rank, wsm, off, Ybf);
  k_fin<<<dim3(16, 16), 256, 0, stream>>>(Ybf, Uod2T, out);
}

// Round 11
// 204.619 us; speedup vs baseline: 1.2502x; 1.2502x over previous
//
#include <hip/hip_runtime.h>
#include <hip/hip_bf16.h>
#include <math.h>

// Tucker MoE: T=1024, D=1024, DFF=1024, R=64, G=8, E=32, NEXP=256, K=8, F=8192
// Round 11: revert R10's fused router (103us: LDS-broadcast pipe saturation at
// 2 blocks/CU — same failure class as R4) back to the R9 structure (201.9us
// known-good), with one bit-identical tweak: explicit float4 LDS reads in the
// router inner loop (ds_read_b128 instead of 4x ds_read_b32; summation order
// per accumulator unchanged -> logits/selection bit-identical).
// 7 dispatches:
//  L1 k_prep_logits : casts/transposes + cnt zero || router logits (fp32)
//  L2 k_pre_topk    : pre MFMA (split-K 2) || top-k + softmax + rank
//  L3 k_scan        : 256-entry scan -> off
//  L4 k_core_gu     : f-indexed fold pre + gate/up core (fp32) -> xgb/xub[p]
//  L5 k_fused_ad    : act(gate/up MFMA + silu*mul in LDS) fused w/ down MFMA
//  L6 k_down_accY   : fold xdp + down core + weighted token fold -> Y bf16
//  L7 k_fin         : dense out = Y[1024,512] @ Uod2[512,1024] (bf16 MFMA)

#define T_ 1024
#define D_ 1024
#define DFF_ 1024
#define R_ 64
#define G_ 8
#define E_ 32
#define NEXP_ 256
#define K_ 8
#define F_ 8192
#define LKZ_ 8   // router split-K (chunks of 128)
#define LTB_ 8   // router tokens per block
#define PKZ_ 2   // k_pre split-K
#define DKZ_ 4   // down split-K (chunks of 256 over DFF)
#define LP_ 72   // LDS tile pitch in bf16 elems (16B rows, 2-way bank alias = free)

typedef short bf16x8 __attribute__((ext_vector_type(8)));
typedef float f32x4 __attribute__((ext_vector_type(4)));

__device__ __forceinline__ unsigned short f2bf(float f) {
  unsigned int u = __float_as_uint(f);
  u += 0x7fffu + ((u >> 16) & 1u);  // RNE (finite inputs)
  return (unsigned short)(u >> 16);
}

__device__ __forceinline__ void stage_tile(short* dst, const unsigned short* src,
                                           int gp, int tid) {
  for (int idx = tid; idx < 512; idx += 256) {
    int r = idx >> 3, c8 = (idx & 7) << 3;
    *(uint4*)&dst[r * LP_ + c8] = *(const uint4*)&src[(size_t)r * gp + c8];
  }
}

__device__ __forceinline__ void stage_tile_guard(short* dst, const unsigned short* src,
                                                 int gp, int rows_valid, int tid) {
  for (int idx = tid; idx < 512; idx += 256) {
    int r = idx >> 3, c8 = (idx & 7) << 3;
    uint4 v = make_uint4(0u, 0u, 0u, 0u);
    if (r < rows_valid) v = *(const uint4*)&src[(size_t)r * gp + c8];
    *(uint4*)&dst[r * LP_ + c8] = v;
  }
}

// Wave computes a 16x64 strip (rows [ms,ms+16)) over K=64 from LDS tiles
// As (rows=m, k-contig) and Bs (rows=n, k-contig; i.e. B^T).
__device__ __forceinline__ void mma_strip(const short* As, const short* Bs,
                                          int ms, int lane, f32x4* acc) {
  int lm = lane & 15;
  int lk = (lane >> 4) << 3;
#pragma unroll
  for (int kc = 0; kc < 64; kc += 32) {
    bf16x8 a = *(const bf16x8*)&As[(ms + lm) * LP_ + kc + lk];
#pragma unroll
    for (int nt = 0; nt < 4; ++nt) {
      bf16x8 b = *(const bf16x8*)&Bs[(nt * 16 + lm) * LP_ + kc + lk];
      acc[nt] = __builtin_amdgcn_mfma_f32_16x16x32_bf16(a, b, acc[nt], 0, 0, 0);
    }
  }
}

// ---------------------------------------------------------------- L1: prep || logits
// 1D grid of 1920 blocks: b<896 = prep roles (id=b>>7: 0..4 cast+T,
// id 5 = uout_down -> Uod2T[d][g*64+r]; 6 = x cast + cnt zero);
// b>=896 = router logits split-K (1024 blocks).
__global__ __launch_bounds__(256) void k_prep_logits(
    const float* __restrict__ x, const float* __restrict__ Wg,
    const float* __restrict__ s0, const float* __restrict__ s1,
    const float* __restrict__ s2, const float* __restrict__ s3,
    const float* __restrict__ s4, const float* __restrict__ s5,
    unsigned short* __restrict__ xb,
    unsigned short* __restrict__ d0, unsigned short* __restrict__ d1,
    unsigned short* __restrict__ d2, unsigned short* __restrict__ d3,
    unsigned short* __restrict__ d4, unsigned short* __restrict__ d5,
    int* __restrict__ cnt, float* __restrict__ lp) {
  __shared__ float shbuf[64 * 65];  // prep: ts[64][65]; logits: xs[8][128]
  int b = blockIdx.x;
  if (b < 896) {
    int id = b >> 7, rem = b & 127, g = rem >> 4, tile = rem & 15;
    if (id == 6) {
      size_t base = ((size_t)g * 16 + tile) * 8192;
      for (int i = threadIdx.x; i < 2048; i += 256) {
        size_t idx = base + (size_t)i * 4;
        float4 v = *(const float4*)&x[idx];
        xb[idx + 0] = f2bf(v.x);
        xb[idx + 1] = f2bf(v.y);
        xb[idx + 2] = f2bf(v.z);
        xb[idx + 3] = f2bf(v.w);
      }
      if (g == 0 && tile == 0) cnt[threadIdx.x] = 0;
      return;
    }
    const float* src = id == 0 ? s0 : id == 1 ? s1 : id == 2 ? s2 : id == 3 ? s3 : id == 4 ? s4 : s5;
    unsigned short* dst = id == 0 ? d0 : id == 1 ? d1 : id == 2 ? d2 : id == 3 ? d3 : id == 4 ? d4 : d5;
    if (id < 3) {
      // uin*: src [g][1024][64] -> dst [g][64][1024]
      int r0 = tile * 64;
      for (int idx = threadIdx.x; idx < 4096; idx += 256) {
        int r = idx >> 6, c = idx & 63;
        shbuf[r * 65 + c] = src[((size_t)g * 1024 + r0 + r) * 64 + c];
      }
      __syncthreads();
      for (int idx = threadIdx.x; idx < 4096; idx += 256) {
        int c = idx >> 6, r = idx & 63;
        dst[((size_t)g * 64 + c) * 1024 + r0 + r] = f2bf(shbuf[r * 65 + c]);
      }
    } else {
      // uout*: src [g][64][1024]; id 3/4 -> [g][1024][64]; id 5 -> [d][g*64+r]
      int c0 = tile * 64;
      for (int idx = threadIdx.x; idx < 4096; idx += 256) {
        int r = idx >> 6, c = idx & 63;
        shbuf[r * 65 + c] = src[((size_t)g * 64 + r) * 1024 + c0 + c];
      }
      __syncthreads();
      if (id == 5) {
        for (int idx = threadIdx.x; idx < 4096; idx += 256) {
          int c = idx >> 6, r = idx & 63;
          dst[(size_t)(c0 + c) * 512 + g * 64 + r] = f2bf(shbuf[r * 65 + c]);
        }
      } else {
        for (int idx = threadIdx.x; idx < 4096; idx += 256) {
          int c = idx >> 6, r = idx & 63;
          dst[((size_t)g * 1024 + c0 + c) * 64 + r] = f2bf(shbuf[r * 65 + c]);
        }
      }
    }
    return;
  }
  // ---- router logits: lp[z][t][e], 8 tokens/block, K-chunk of 128
  int lb = b - 896;
  int t0 = (lb & 127) * LTB_;
  int z = lb >> 7;
  int e = threadIdx.x;
  float* xs = shbuf;  // [8][128]
  float a[LTB_] = {};
  int dc = z * 128;
  {
    int idx = threadIdx.x * 4;  // 256 thr x float4 = the whole 8x128 tile
    int tl = idx >> 7, d = idx & 127;
    *(float4*)&xs[tl * 128 + d] = *(const float4*)&x[(size_t)(t0 + tl) * D_ + dc + d];
  }
  __syncthreads();
  // float4 LDS reads (ds_read_b128); per-accumulator FMA order is still
  // d2-ascending -> bit-identical logits vs the R6/R9 router.
#pragma unroll 2
  for (int d2 = 0; d2 < 128; d2 += 4) {
    float w0 = Wg[(size_t)(dc + d2 + 0) * NEXP_ + e];
    float w1 = Wg[(size_t)(dc + d2 + 1) * NEXP_ + e];
    float w2 = Wg[(size_t)(dc + d2 + 2) * NEXP_ + e];
    float w3 = Wg[(size_t)(dc + d2 + 3) * NEXP_ + e];
#pragma unroll
    for (int j = 0; j < LTB_; ++j) {
      float4 xv = *(const float4*)&xs[j * 128 + d2];
      a[j] = fmaf(xv.x, w0, a[j]);
      a[j] = fmaf(xv.y, w1, a[j]);
      a[j] = fmaf(xv.z, w2, a[j]);
      a[j] = fmaf(xv.w, w3, a[j]);
    }
  }
  size_t base = (size_t)z * T_ * NEXP_;
#pragma unroll
  for (int j = 0; j < LTB_; ++j)
    lp[base + (size_t)(t0 + j) * NEXP_ + e] = a[j];
}

// ---------------------------------------------------------------- L2: pre MFMA || topk (+rank)
__global__ __launch_bounds__(256) void k_pre_topk(
    const unsigned short* __restrict__ xb,
    const unsigned short* __restrict__ uinT_g, const unsigned short* __restrict__ uinT_u,
    const float* __restrict__ lp,
    float* __restrict__ Pgp, float* __restrict__ Pup,
    int* __restrict__ sel, float* __restrict__ wsm,
    int* __restrict__ rank, int* __restrict__ cnt) {
  __shared__ short sh2[2 * 64 * LP_];
  int b = blockIdx.x;
  if (b < 512) {
    int tile = b & 15, g = (b >> 4) & 7, zz = b >> 7;
    int gu = zz >> 1, kz = zz & 1;
    const unsigned short* U = gu ? uinT_u : uinT_g;  // [G][64(r)][1024(d)]
    float* P = gu ? Pup : Pgp;
    int t0 = tile * 64;
    short* As = sh2;
    short* Bs = sh2 + 64 * LP_;
    int tid = threadIdx.x, lane = tid & 63, ms = (tid >> 6) * 16;
    f32x4 acc[4] = {};
    int dlo = kz * (D_ / PKZ_);
    for (int dc = dlo; dc < dlo + D_ / PKZ_; dc += 64) {
      stage_tile(As, xb + (size_t)t0 * D_ + dc, D_, tid);
      stage_tile(Bs, U + (size_t)g * 64 * 1024 + dc, 1024, tid);
      __syncthreads();
      mma_strip(As, Bs, ms, lane, acc);
      __syncthreads();
    }
    int lm = lane & 15, lq = (lane >> 4) * 4;
#pragma unroll
    for (int nt = 0; nt < 4; ++nt)
#pragma unroll
      for (int r = 0; r < 4; ++r)
        P[((size_t)(kz * G_ + g) * T_ + t0 + ms + lq + r) * R_ + nt * 16 + lm] = acc[nt][r];
    return;
  }
  // ---- topk: one wave per token, folds the LKZ_ logits partials on load
  int tb = b - 512;
  int wave = threadIdx.x >> 6;
  int lane = threadIdx.x & 63;
  int t = tb * 4 + wave;
  float v[4];
  int idx[4];
#pragma unroll
  for (int j = 0; j < 4; ++j) {
    idx[j] = lane + 64 * j;
    float s = 0.f;
#pragma unroll
    for (int z = 0; z < LKZ_; ++z)
      s += lp[(size_t)z * T_ * NEXP_ + (size_t)t * NEXP_ + idx[j]];
    v[j] = s;
  }
  float topv[K_];
  int topi[K_];
#pragma unroll
  for (int k = 0; k < K_; ++k) {
    float bv = v[0];
    int bi = idx[0];
#pragma unroll
    for (int j = 1; j < 4; ++j)
      if (v[j] > bv || (v[j] == bv && idx[j] < bi)) { bv = v[j]; bi = idx[j]; }
#pragma unroll
    for (int off = 32; off > 0; off >>= 1) {
      float ov = __shfl_xor(bv, off);
      int oi = __shfl_xor(bi, off);
      if (ov > bv || (ov == bv && oi < bi)) { bv = ov; bi = oi; }
    }
    topv[k] = bv;
    topi[k] = bi;
#pragma unroll
    for (int j = 0; j < 4; ++j)
      if (idx[j] == bi) v[j] = -INFINITY;
  }
  float m = topv[0];
  float ev[K_];
  float s = 0.f;
#pragma unroll
  for (int k = 0; k < K_; ++k) { ev[k] = expf(topv[k] - m); s += ev[k]; }
  float inv = 1.f / s;
  if (lane < K_) {
    sel[t * K_ + lane] = topi[lane];
    wsm[t * K_ + lane] = ev[lane] * inv;
    rank[t * K_ + lane] = atomicAdd(&cnt[topi[lane]], 1);  // keep the rank!
  }
}

// ---------------------------------------------------------------- L3: bare 256-entry scan -> off
__global__ __launch_bounds__(256) void k_scan(const int* __restrict__ cnt,
                                              int* __restrict__ off) {
  __shared__ int s[NEXP_];
  int i = threadIdx.x;
  s[i] = cnt[i];
  __syncthreads();
  for (int d = 1; d < NEXP_; d <<= 1) {
    int v = (i >= d) ? s[i - d] : 0;
    __syncthreads();
    s[i] += v;
    __syncthreads();
  }
  off[i + 1] = s[i];
  if (i == 0) off[0] = 0;
}

// ---------------------------------------------------------------- L4: f-indexed fold pre + gate/up core -> xgb/xub[p]
__global__ __launch_bounds__(256) void k_core_gu(const float* __restrict__ Pgp,
                                                 const float* __restrict__ Pup,
                                                 const float* __restrict__ core_g,
                                                 const float* __restrict__ core_u,
                                                 const int* __restrict__ sel,
                                                 const int* __restrict__ rank,
                                                 const int* __restrict__ off,
                                                 unsigned short* __restrict__ xgb,
                                                 unsigned short* __restrict__ xub) {
  int pl = threadIdx.x >> 6;
  int o = threadIdx.x & 63;
  int f = blockIdx.x * 4 + pl;
  int t = f >> 3;
  int e = sel[f];
  int g = e >> 5;
  int p = off[e] + rank[f];
  __shared__ float rg[4][64], ru[4][64];
  float sg = 0.f, su = 0.f;
#pragma unroll
  for (int kz = 0; kz < PKZ_; ++kz) {
    sg += Pgp[((size_t)(kz * G_ + g) * T_ + t) * R_ + o];
    su += Pup[((size_t)(kz * G_ + g) * T_ + t) * R_ + o];
  }
  rg[pl][o] = sg;
  ru[pl][o] = su;
  __syncthreads();
  const float* cg = core_g + (size_t)e * R_ * R_;
  const float* cu = core_u + (size_t)e * R_ * R_;
  float ag = 0.f, au = 0.f;
#pragma unroll 8
  for (int r = 0; r < R_; ++r) {
    ag = fmaf(rg[pl][r], cg[r * R_ + o], ag);
    au = fmaf(ru[pl][r], cu[r * R_ + o], au);
  }
  xgb[(size_t)p * R_ + o] = f2bf(ag);
  xub[(size_t)p * R_ + o] = f2bf(au);
}

// ---------------------------------------------------------------- L5: fused act+down (MFMA)
__global__ __launch_bounds__(256) void k_fused_ad(const unsigned short* __restrict__ xgb,
                                                  const unsigned short* __restrict__ xub,
                                                  const unsigned short* __restrict__ uoutT_g,
                                                  const unsigned short* __restrict__ uoutT_u,
                                                  const unsigned short* __restrict__ uinT_d,
                                                  const int* __restrict__ off,
                                                  float* __restrict__ xdp) {
  int g = blockIdx.y;
  int kz = blockIdx.z;
  int p0 = off[g * E_];
  int pend = off[g * E_ + E_];
  int ntiles = (pend - p0 + 63) >> 6;
  __shared__ short Ag[64 * LP_], Au[64 * LP_];
  __shared__ short Bg[64 * LP_], Bu[64 * LP_], Bd[64 * LP_];
  __shared__ short Pt[64 * LP_];
  int tid = threadIdx.x, lane = tid & 63, ms = (tid >> 6) * 16;
  int lm = lane & 15, lq = (lane >> 4) * 4;
  for (int tile = blockIdx.x; tile < ntiles; tile += gridDim.x) {
    int pbase = p0 + tile * 64;
    int rv = pend - pbase; if (rv > 64) rv = 64;
    stage_tile_guard(Ag, xgb + (size_t)pbase * R_, R_, rv, tid);
    stage_tile_guard(Au, xub + (size_t)pbase * R_, R_, rv, tid);
    f32x4 accd[4] = {};
#pragma unroll
    for (int c4 = 0; c4 < 4; ++c4) {
      int cc = kz * (DFF_ / DKZ_) + c4 * 64;
      stage_tile(Bg, uoutT_g + ((size_t)g * DFF_ + cc) * R_, R_, tid);
      stage_tile(Bu, uoutT_u + ((size_t)g * DFF_ + cc) * R_, R_, tid);
      stage_tile(Bd, uinT_d + (size_t)g * 64 * 1024 + cc, 1024, tid);
      __syncthreads();
      f32x4 accg[4] = {}, accu[4] = {};
      mma_strip(Ag, Bg, ms, lane, accg);
      mma_strip(Au, Bu, ms, lane, accu);
#pragma unroll
      for (int nt = 0; nt < 4; ++nt)
#pragma unroll
        for (int r = 0; r < 4; ++r) {
          float gv = accg[nt][r];
          float av = gv / (1.f + expf(-gv)) * accu[nt][r];
          Pt[(ms + lq + r) * LP_ + nt * 16 + lm] = (short)f2bf(av);
        }
      mma_strip(Pt, Bd, ms, lane, accd);  // reads only own-wave rows of Pt
      __syncthreads();
    }
#pragma unroll
    for (int nt = 0; nt < 4; ++nt)
#pragma unroll
      for (int r = 0; r < 4; ++r) {
        int p = pbase + ms + lq + r;
        if (p < pend) xdp[((size_t)kz * F_ + p) * R_ + nt * 16 + lm] = accd[nt][r];
      }
    __syncthreads();
  }
}

// ---------------------------------------------------------------- L6: fold xdp + down core + token fold -> Y bf16
// 1024 blocks = 1 token each. Wave w handles k = 2w, 2w+1 (lane = r/output o).
__global__ __launch_bounds__(256) void k_down_accY(const float* __restrict__ xdp,
                                                   const float* __restrict__ core_d,
                                                   const int* __restrict__ sel,
                                                   const int* __restrict__ rank,
                                                   const float* __restrict__ wsm,
                                                   const int* __restrict__ off,
                                                   unsigned short* __restrict__ Ybf) {
  int t = blockIdx.x;
  int w = threadIdx.x >> 6, o = threadIdx.x & 63;
  __shared__ float xs[4][64];
  __shared__ float yl[4][G_][64];
  float y[G_] = {};
#pragma unroll
  for (int kk = 0; kk < 2; ++kk) {
    int f = t * K_ + w * 2 + kk;
    int e = sel[f];
    int g = e >> 5;
    int p = off[e] + rank[f];
    float s = 0.f;
#pragma unroll
    for (int kz = 0; kz < DKZ_; ++kz) s += xdp[((size_t)kz * F_ + p) * R_ + o];
    __syncthreads();
    xs[w][o] = s;
    __syncthreads();
    const float* cd = core_d + (size_t)e * R_ * R_;
    float a = 0.f;
#pragma unroll 8
    for (int r = 0; r < R_; ++r) a = fmaf(xs[w][r], cd[r * R_ + o], a);
    y[g] += wsm[f] * a;
  }
#pragma unroll
  for (int g = 0; g < G_; ++g) yl[w][g][o] = y[g];
  __syncthreads();
  for (int idx = threadIdx.x; idx < 512; idx += 256) {
    int g = idx >> 6, oo = idx & 63;
    float v = yl[0][g][oo] + yl[1][g][oo] + yl[2][g][oo] + yl[3][g][oo];
    Ybf[(size_t)t * 512 + g * 64 + oo] = f2bf(v);
  }
}

// ---------------------------------------------------------------- L7: out = Y[1024,512] @ Uod2[512,1024], dense MFMA
__global__ __launch_bounds__(256) void k_fin(const unsigned short* __restrict__ Ybf,
                                             const unsigned short* __restrict__ Uod2T,
                                             float* __restrict__ out) {
  int t0 = blockIdx.x * 64;
  int d0 = blockIdx.y * 64;
  __shared__ short As[64 * LP_], Bs[64 * LP_];
  __shared__ float Os[64 * 68];
  int tid = threadIdx.x, lane = tid & 63, ms = (tid >> 6) * 16;
  int lm = lane & 15, lq = (lane >> 4) * 4;
  f32x4 acc[4] = {};
  for (int kc = 0; kc < 512; kc += 64) {
    stage_tile(As, Ybf + (size_t)t0 * 512 + kc, 512, tid);
    stage_tile(Bs, Uod2T + (size_t)d0 * 512 + kc, 512, tid);
    __syncthreads();
    mma_strip(As, Bs, ms, lane, acc);
    __syncthreads();
  }
#pragma unroll
  for (int nt = 0; nt < 4; ++nt)
#pragma unroll
    for (int r = 0; r < 4; ++r)
      Os[(ms + lq + r) * 68 + nt * 16 + lm] = acc[nt][r];
  __syncthreads();
  for (int idx = tid; idx < 1024; idx += 256) {
    int r = idx >> 4, c4 = (idx & 15) << 2;
    *(float4*)&out[(size_t)(t0 + r) * D_ + d0 + c4] = *(const float4*)&Os[r * 68 + c4];
  }
}

// ================================================================ launch
extern "C" void kernel_launch(void* const* d_in, const int* in_sizes, int n_in,
                              void* d_out, int out_size, void* d_ws, size_t ws_size,
                              hipStream_t stream) {
  const float* x = (const float*)d_in[0];
  const float* Wg = (const float*)d_in[1];
  const float* uin_gate = (const float*)d_in[2];
  const float* core_gate = (const float*)d_in[3];
  const float* uout_gate = (const float*)d_in[4];
  const float* uin_up = (const float*)d_in[5];
  const float* core_up = (const float*)d_in[6];
  const float* uout_up = (const float*)d_in[7];
  const float* uin_down = (const float*)d_in[8];
  const float* core_down = (const float*)d_in[9];
  const float* uout_down = (const float*)d_in[10];
  float* out = (float*)d_out;

  char* ws = (char*)d_ws;
  size_t o = 0;
  auto alloc = [&](size_t bytes) { size_t r = o; o = (o + bytes + 255) & ~(size_t)255; return r; };
  size_t o_lp = alloc((size_t)LKZ_ * T_ * NEXP_ * 4);           // 8 MB
  size_t o_sel = alloc(F_ * 4);
  size_t o_wsm = alloc(F_ * 4);
  size_t o_rank = alloc(F_ * 4);
  size_t o_cnt = alloc(NEXP_ * 4);
  size_t o_off = alloc((NEXP_ + 1) * 4);
  size_t o_xb = alloc((size_t)T_ * D_ * 2);                     // 2 MB
  size_t o_uinT_g = alloc((size_t)G_ * 64 * 1024 * 2);          // 1 MB each
  size_t o_uinT_u = alloc((size_t)G_ * 64 * 1024 * 2);
  size_t o_uinT_d = alloc((size_t)G_ * 64 * 1024 * 2);
  size_t o_uoutT_g = alloc((size_t)G_ * 1024 * 64 * 2);
  size_t o_uoutT_u = alloc((size_t)G_ * 1024 * 64 * 2);
  size_t o_Uod2T = alloc((size_t)D_ * 512 * 2);                 // 1 MB
  size_t o_xgb = alloc((size_t)F_ * R_ * 2);                    // 1 MB
  size_t o_xub = alloc((size_t)F_ * R_ * 2);
  size_t o_Y = alloc((size_t)T_ * 512 * 2);                     // 1 MB
  size_t o_pgp = alloc((size_t)PKZ_ * G_ * T_ * R_ * 4);        // 4 MB
  size_t o_pup = alloc((size_t)PKZ_ * G_ * T_ * R_ * 4);        // 4 MB
  size_t o_xdp = alloc((size_t)DKZ_ * F_ * R_ * 4);             // 8 MB
  (void)ws_size;

  float* lp = (float*)(ws + o_lp);
  int* sel = (int*)(ws + o_sel);
  float* wsm = (float*)(ws + o_wsm);
  int* rank = (int*)(ws + o_rank);
  int* cnt = (int*)(ws + o_cnt);
  int* off = (int*)(ws + o_off);
  unsigned short* xb = (unsigned short*)(ws + o_xb);
  unsigned short* uinT_g = (unsigned short*)(ws + o_uinT_g);
  unsigned short* uinT_u = (unsigned short*)(ws + o_uinT_u);
  unsigned short* uinT_d = (unsigned short*)(ws + o_uinT_d);
  unsigned short* uoutT_g = (unsigned short*)(ws + o_uoutT_g);
  unsigned short* uoutT_u = (unsigned short*)(ws + o_uoutT_u);
  unsigned short* Uod2T = (unsigned short*)(ws + o_Uod2T);
  unsigned short* xgb = (unsigned short*)(ws + o_xgb);
  unsigned short* xub = (unsigned short*)(ws + o_xub);
  unsigned short* Ybf = (unsigned short*)(ws + o_Y);
  float* pgp = (float*)(ws + o_pgp);
  float* pup = (float*)(ws + o_pup);
  float* xdp = (float*)(ws + o_xdp);

  k_prep_logits<<<1920, 256, 0, stream>>>(x, Wg, uin_gate, uin_up, uin_down,
                                          uout_gate, uout_up, uout_down, xb,
                                          uinT_g, uinT_u, uinT_d,
                                          uoutT_g, uoutT_u, Uod2T, cnt, lp);
  k_pre_topk<<<768, 256, 0, stream>>>(xb, uinT_g, uinT_u, lp, pgp, pup, sel, wsm, rank, cnt);
  k_scan<<<1, 256, 0, stream>>>(cnt, off);
  k_core_gu<<<F_ / 4, 256, 0, stream>>>(pgp, pup, core_gate, core_up, sel, rank, off, xgb, xub);
  k_fused_ad<<<dim3(16, G_, DKZ_), 256, 0, stream>>>(xgb, xub, uoutT_g, uoutT_u, uinT_d, off, xdp);
  k_down_accY<<<T_, 256, 0, stream>>>(xdp, core_down, sel, rank, wsm, off, Ybf);
  k_fin<<<dim3(16, 16), 256, 0, stream>>>(Ybf, Uod2T, out);
}